// Round 6
// baseline (1596.168 us; speedup 1.0000x reference)
//
#include <hip/hip_runtime.h>
#include <float.h>

#define NB 16
#define NP 1024
#define NROW (NB*NP)
#define NCH 4      // j-chunks per cloud for kNN scan

// ---------------------------------------------------------------- init
__global__ void k_init(float* colsum, float* colsq, float* pmax, float* pmin) {
    int i = blockIdx.x * 256 + threadIdx.x;          // grid 256 -> i < 65536
    if (i < 1024) { colsum[i] = 0.f; colsq[i] = 0.f; }
    pmax[i] = -FLT_MAX;
    pmin[i] =  FLT_MAX;
}

// ---------------------------------------------------------------- weight prep
// wc[kk, c] = (c<dout) ? Wtop-Wbot : Wbot ;  b2 = [b, 0]
__global__ void k_prep(const float* __restrict__ W, const float* __restrict__ b,
                       float* __restrict__ wc, float* __restrict__ b2, int d, int dout) {
    int n2 = 2 * dout;
    int i = blockIdx.x * 256 + threadIdx.x;
    if (i < d * n2) {
        int kk = i / n2, c = i % n2;
        wc[i] = (c < dout) ? (W[kk * dout + c] - W[(kk + d) * dout + c])
                           : W[(kk + d) * dout + (c - dout)];
    }
    if (i < n2) b2[i] = (i < dout) ? b[i] : 0.f;
}

// ---------------------------------------------------------------- squared norms
__global__ void k_sqnorm(const float* __restrict__ x, int stride, int D, float* __restrict__ sq) {
    int row = blockIdx.x * 4 + (threadIdx.x >> 6);
    int lane = threadIdx.x & 63;
    const float* xr = x + (size_t)row * stride;
    float s = 0.f;
    for (int kk = lane; kk < D; kk += 64) { float v = xr[kk]; s += v * v; }
    for (int o = 32; o; o >>= 1) s += __shfl_down(s, o);
    if (lane == 0) sq[row] = s;
}

// ---------------------------------------------------------------- float -> order-preserving u32
__device__ inline unsigned ford(float f) {
    unsigned u = __float_as_uint(f);
    return (u & 0x80000000u) ? ~u : (u | 0x80000000u);
}

// ---------------------------------------------------------------- kNN scan (chunked): per (row, chunk) top-20
// block 256 = 4 waves; 64 rows (lane = row); each wave handles 1/4 of each 32-j tile; 256 j's per chunk.
template<int D>
__global__ __launch_bounds__(256, 2) void k_knn_scan(const float* __restrict__ x, int stride,
                                                     const float* __restrict__ sq,
                                                     unsigned long long* __restrict__ cand) {
    constexpr int TJ = 32;
    constexpr int XJ = TJ * D;
    constexpr int MERGE = 20 * 64 * 2;
    constexpr int SM = (XJ > MERGE) ? XJ : MERGE;
    __shared__ __align__(16) float smem[SM];
    __shared__ float sqj[TJ];
    __shared__ float topd[20 * 256];              // 20KB
    __shared__ unsigned short topi[20 * 256];     // 10KB

    const int b = blockIdx.y;
    const int r0 = blockIdx.x * 64;
    const int ch = blockIdx.z;
    const int j0 = ch * (NP / NCH);               // 256 j's per chunk
    const int tid = threadIdx.x;
    const int wave = tid >> 6, lane = tid & 63;
    const int row = r0 + lane;

    const float* xr = x + (size_t)(b * NP + row) * stride;
    float xi[D];
#pragma unroll
    for (int kk = 0; kk < D; kk++) xi[kk] = xr[kk];

#pragma unroll
    for (int t = 0; t < 20; t++) topd[t * 256 + tid] = FLT_MAX;
    float curmax = FLT_MAX; int maxpos = 0;

    for (int jt = 0; jt < (NP / NCH) / TJ; jt++) {     // 8 tiles
        __syncthreads();
        if constexpr (D % 4 == 0) {
            constexpr int D4 = D / 4;
            float4* xj4 = (float4*)smem;
            for (int e = tid; e < TJ * D4; e += 256) {
                int jj = e / D4, kq = e % D4;
                xj4[e] = *(const float4*)(x + (size_t)(b * NP + j0 + jt * TJ + jj) * stride + kq * 4);
            }
        } else {
            for (int e = tid; e < TJ * D; e += 256) {
                int jj = e / D, kk = e % D;
                smem[e] = x[(size_t)(b * NP + j0 + jt * TJ + jj) * stride + kk];
            }
        }
        if (tid < TJ) sqj[tid] = sq[b * NP + j0 + jt * TJ + tid];
        __syncthreads();

#pragma unroll 1
        for (int u = 0; u < TJ / 4; u++) {
            int jj = wave * (TJ / 4) + u;
            float key;
            if constexpr (D % 4 == 0) {
                const float4* xv = ((const float4*)smem) + jj * (D / 4);
                float a0 = 0.f, a1 = 0.f, a2 = 0.f, a3 = 0.f;
#pragma unroll
                for (int kq = 0; kq < D / 4; kq++) {
                    float4 v = xv[kq];
                    a0 += xi[4 * kq + 0] * v.x;
                    a1 += xi[4 * kq + 1] * v.y;
                    a2 += xi[4 * kq + 2] * v.z;
                    a3 += xi[4 * kq + 3] * v.w;
                }
                key = sqj[jj] - 2.f * ((a0 + a1) + (a2 + a3));
            } else {
                float acc = 0.f;
#pragma unroll
                for (int kk = 0; kk < D; kk++) acc += xi[kk] * smem[jj * D + kk];
                key = sqj[jj] - 2.f * acc;
            }
            if (key < curmax) {
                topd[maxpos * 256 + tid] = key;
                topi[maxpos * 256 + tid] = (unsigned short)(j0 + jt * TJ + jj);
                float m = -FLT_MAX; int mp = 0;
#pragma unroll
                for (int t = 0; t < 20; t++) {
                    float v = topd[t * 256 + tid];
                    if (v > m) { m = v; mp = t; }
                }
                curmax = m; maxpos = mp;
            }
        }
    }
    __syncthreads();

    if (tid < 64) {   // merge 4 per-wave lists of 20 -> chunk top-20, pack to u64
        float* fd = smem;
        int* fi = (int*)(smem + 20 * 64);
        float fm = FLT_MAX; int fp = 0;
#pragma unroll
        for (int t = 0; t < 20; t++) fd[t * 64 + tid] = FLT_MAX;
        for (int w = 0; w < 4; w++) {
#pragma unroll 1
            for (int t = 0; t < 20; t++) {
                float key = topd[t * 256 + w * 64 + tid];
                if (key < fm) {
                    fd[fp * 64 + tid] = key;
                    fi[fp * 64 + tid] = (int)topi[t * 256 + w * 64 + tid];
                    float m = -FLT_MAX; int mp = 0;
#pragma unroll
                    for (int t2 = 0; t2 < 20; t2++) {
                        float v = fd[t2 * 64 + tid];
                        if (v > m) { m = v; mp = t2; }
                    }
                    fm = m; fp = mp;
                }
            }
        }
#pragma unroll
        for (int t = 0; t < 20; t++) {
            unsigned long long v = ((unsigned long long)ford(fd[t * 64 + tid]) << 32)
                                 | (unsigned)fi[t * 64 + tid];
            cand[((size_t)(b * NP + r0 + tid) * NCH + ch) * 20 + t] = v;
        }
    }
}

// ---------------------------------------------------------------- kNN merge: 4 chunk-lists (80) -> final 20
__global__ void k_knn_merge(const unsigned long long* __restrict__ cand, int* __restrict__ idxout) {
    int row = blockIdx.x * 256 + threadIdx.x;   // 16384
    const unsigned long long* cp = cand + (size_t)row * (NCH * 20);
    unsigned long long last = 0;
#pragma unroll 1
    for (int t = 0; t < 20; t++) {
        unsigned long long m = 0xFFFFFFFFFFFFFFFFULL;
#pragma unroll
        for (int c = 0; c < NCH * 20; c++) {
            unsigned long long v = cp[c];
            if (v > last && v < m) m = v;
        }
        idxout[(size_t)row * 20 + t] = (int)(unsigned)(m & 0xFFFFFFFFu);
        last = m;
    }
}

// ---------------------------------------------------------------- p/q GEMM:  pq = x @ wc + b2
#define FMA16(a, bv) do { \
    acc[0].x += (a).x*(bv).x; acc[0].y += (a).x*(bv).y; acc[0].z += (a).x*(bv).z; acc[0].w += (a).x*(bv).w; \
    acc[1].x += (a).y*(bv).x; acc[1].y += (a).y*(bv).y; acc[1].z += (a).y*(bv).z; acc[1].w += (a).y*(bv).w; \
    acc[2].x += (a).z*(bv).x; acc[2].y += (a).z*(bv).y; acc[2].z += (a).z*(bv).z; acc[2].w += (a).z*(bv).w; \
    acc[3].x += (a).w*(bv).x; acc[3].y += (a).w*(bv).y; acc[3].z += (a).w*(bv).z; acc[3].w += (a).w*(bv).w; \
} while (0)

template<int D, int DOUT>
__global__ __launch_bounds__(256) void k_gemm_pq(const float* __restrict__ x, int stride,
                                                 const float* __restrict__ wc, const float* __restrict__ b2,
                                                 float* __restrict__ pq) {
    constexpr int N2 = 2 * DOUT;
    constexpr int KC = (D > 64) ? 64 : D;
    __shared__ __align__(16) float At[KC * 68];
    __shared__ __align__(16) float Bs[KC * 64];
    const int tid = threadIdx.x;
    const int tx = tid & 15, ty = tid >> 4;
    const int r0 = blockIdx.x * 64;
    const int c0 = blockIdx.y * 64;

    float4 acc[4] = {};
    for (int k0 = 0; k0 < D; k0 += KC) {
        __syncthreads();
        if constexpr (KC % 4 == 0) {
            constexpr int K4 = KC / 4;
            for (int e = tid; e < 64 * K4; e += 256) {
                int rr = e / K4, kq = e % K4;
                float4 v = *(const float4*)(x + (size_t)(r0 + rr) * stride + k0 + kq * 4);
                At[(4 * kq + 0) * 68 + rr] = v.x;
                At[(4 * kq + 1) * 68 + rr] = v.y;
                At[(4 * kq + 2) * 68 + rr] = v.z;
                At[(4 * kq + 3) * 68 + rr] = v.w;
            }
        } else {
            for (int e = tid; e < 64 * KC; e += 256) {
                int rr = e / KC, kk = e % KC;
                At[kk * 68 + rr] = x[(size_t)(r0 + rr) * stride + k0 + kk];
            }
        }
        for (int e = tid; e < KC * 16; e += 256) {
            int kk = e / 16, cq = e % 16;
            *(float4*)&Bs[kk * 64 + cq * 4] = *(const float4*)(wc + (size_t)(k0 + kk) * N2 + c0 + cq * 4);
        }
        __syncthreads();
#pragma unroll 8
        for (int kk = 0; kk < KC; kk++) {
            float4 a = *(const float4*)&At[kk * 68 + ty * 4];
            float4 bv = *(const float4*)&Bs[kk * 64 + tx * 4];
            FMA16(a, bv);
        }
    }
    float4 bias = *(const float4*)(b2 + c0 + tx * 4);
#pragma unroll
    for (int ri = 0; ri < 4; ri++) {
        float4 o;
        o.x = acc[ri].x + bias.x; o.y = acc[ri].y + bias.y;
        o.z = acc[ri].z + bias.z; o.w = acc[ri].w + bias.w;
        *(float4*)(pq + (size_t)(r0 + ty * 4 + ri) * N2 + c0 + tx * 4) = o;
    }
}

// ---------------------------------------------------------------- gather + max over 20 neighbors
__global__ void k_gather(const float* __restrict__ pq, const int* __restrict__ idx,
                         float* __restrict__ cat_, int log2dout, int off) {
    int gid = blockIdx.x * 256 + threadIdx.x;
    int dout = 1 << log2dout;
    int row = gid >> log2dout;
    int c = gid & (dout - 1);
    int b = row >> 10;
    int s2 = dout * 2;
    const float* qb = pq + (size_t)(b << 10) * s2 + dout + c;
    const int* ip = idx + (size_t)row * 20;
    float m = -FLT_MAX;
#pragma unroll
    for (int t = 0; t < 20; t++) {
        int j = ip[t];
        m = fmaxf(m, qb[(size_t)j * s2]);
    }
    cat_[(size_t)row * 512 + off + c] = pq[(size_t)row * s2 + c] + m;
}

// ---------------------------------------------------------------- fused linear: y = cat@Wl + bl, col stats + per-(b,c) max/min
__global__ __launch_bounds__(256) void k_fused_lin(const float* __restrict__ cat_, const float* __restrict__ Wl,
                                                   const float* __restrict__ bl,
                                                   float* colsum, float* colsq, float* pmax, float* pmin) {
    __shared__ __align__(16) float At[32 * 68];
    __shared__ __align__(16) float Bs[32 * 64];
    __shared__ float red[16 * 64];
    const int tid = threadIdx.x;
    const int tx = tid & 15, ty = tid >> 4;
    const int ct = blockIdx.x, b = blockIdx.y, rs = blockIdx.z;
    const int c0 = ct * 64;

    float4 blv = *(const float4*)(bl + c0 + tx * 4);
    float4 s = {0, 0, 0, 0}, ss = {0, 0, 0, 0};
    float4 mx = {-FLT_MAX, -FLT_MAX, -FLT_MAX, -FLT_MAX};
    float4 mn = {FLT_MAX, FLT_MAX, FLT_MAX, FLT_MAX};

    for (int rt = 0; rt < 4; rt++) {
        int r0 = b * 1024 + rs * 256 + rt * 64;
        float4 acc[4] = {};
        for (int kt = 0; kt < 16; kt++) {
            __syncthreads();
            for (int e = tid; e < 512; e += 256) {
                int rr = e >> 3, kq = e & 7;
                float4 v = *(const float4*)(cat_ + (size_t)(r0 + rr) * 512 + kt * 32 + kq * 4);
                At[(4 * kq + 0) * 68 + rr] = v.x;
                At[(4 * kq + 1) * 68 + rr] = v.y;
                At[(4 * kq + 2) * 68 + rr] = v.z;
                At[(4 * kq + 3) * 68 + rr] = v.w;
            }
            for (int e = tid; e < 512; e += 256) {
                int kk = e >> 4, cq = e & 15;
                *(float4*)&Bs[kk * 64 + cq * 4] = *(const float4*)(Wl + (size_t)(kt * 32 + kk) * 1024 + c0 + cq * 4);
            }
            __syncthreads();
#pragma unroll 8
            for (int kk = 0; kk < 32; kk++) {
                float4 a = *(const float4*)&At[kk * 68 + ty * 4];
                float4 bv = *(const float4*)&Bs[kk * 64 + tx * 4];
                FMA16(a, bv);
            }
        }
#pragma unroll
        for (int ri = 0; ri < 4; ri++) {
            float yx = acc[ri].x + blv.x, yy = acc[ri].y + blv.y;
            float yz = acc[ri].z + blv.z, yw = acc[ri].w + blv.w;
            s.x += yx; ss.x += yx * yx; mx.x = fmaxf(mx.x, yx); mn.x = fminf(mn.x, yx);
            s.y += yy; ss.y += yy * yy; mx.y = fmaxf(mx.y, yy); mn.y = fminf(mn.y, yy);
            s.z += yz; ss.z += yz * yz; mx.z = fmaxf(mx.z, yz); mn.z = fminf(mn.z, yz);
            s.w += yw; ss.w += yw * yw; mx.w = fmaxf(mx.w, yw); mn.w = fminf(mn.w, yw);
        }
    }

    float rsum = 0.f, rss = 0.f, rmx = -FLT_MAX, rmn = FLT_MAX;
    __syncthreads(); *(float4*)&red[ty * 64 + tx * 4] = s;  __syncthreads();
    if (tid < 64) for (int t = 0; t < 16; t++) rsum += red[t * 64 + tid];
    __syncthreads(); *(float4*)&red[ty * 64 + tx * 4] = ss; __syncthreads();
    if (tid < 64) for (int t = 0; t < 16; t++) rss += red[t * 64 + tid];
    __syncthreads(); *(float4*)&red[ty * 64 + tx * 4] = mx; __syncthreads();
    if (tid < 64) for (int t = 0; t < 16; t++) rmx = fmaxf(rmx, red[t * 64 + tid]);
    __syncthreads(); *(float4*)&red[ty * 64 + tx * 4] = mn; __syncthreads();
    if (tid < 64) for (int t = 0; t < 16; t++) rmn = fminf(rmn, red[t * 64 + tid]);

    if (tid < 64) {
        int c = c0 + tid;
        atomicAdd(&colsum[c], rsum);
        atomicAdd(&colsq[c], rss);
        pmax[(size_t)(rs * 16 + b) * 1024 + c] = rmx;
        pmin[(size_t)(rs * 16 + b) * 1024 + c] = rmn;
    }
}

// ---------------------------------------------------------------- BN + leaky + pool (commuted through max/min)
__global__ void k_bnpool(const float* colsum, const float* colsq,
                         const float* pmax, const float* pmin,
                         const float* __restrict__ gl, const float* __restrict__ betal,
                         float* __restrict__ pooled) {
    int gid = blockIdx.x * 256 + threadIdx.x;   // 16384
    int c = gid & 1023, b = gid >> 10;
    float mean = colsum[c] * (1.f / 16384.f);
    float var = colsq[c] * (1.f / 16384.f) - mean * mean;
    float a = gl[c] * rsqrtf(var + 1e-5f);
    float d = betal[c] - mean * a;
    float vmx = -FLT_MAX, vmn = FLT_MAX;
#pragma unroll
    for (int rs = 0; rs < 4; rs++) {
        vmx = fmaxf(vmx, pmax[(size_t)(rs * 16 + b) * 1024 + c]);
        vmn = fminf(vmn, pmin[(size_t)(rs * 16 + b) * 1024 + c]);
    }
    float v = a * ((a >= 0.f) ? vmx : vmn) + d;
    pooled[gid] = v > 0.f ? v : 0.2f * v;
}

// ---------------------------------------------------------------- MLP stage 1
__global__ __launch_bounds__(256) void k_mlp1(const float* __restrict__ pooled, const float* __restrict__ Wm1,
                                              const float* __restrict__ bm1, const float* __restrict__ gm1,
                                              const float* __restrict__ betam1, float* __restrict__ hbuf) {
    int tid = threadIdx.x;
    int r = tid >> 4, cl = tid & 15;
    int c = blockIdx.x * 16 + cl;
    float z = bm1[c];
    const float* pr = pooled + (size_t)r * 1024;
    for (int kk = 0; kk < 1024; kk++) z += pr[kk] * Wm1[(size_t)kk * 512 + c];
    __shared__ float zb[16 * 16];
    zb[r * 16 + cl] = z;
    __syncthreads();
    float sm = 0.f, sq = 0.f;
#pragma unroll
    for (int rr = 0; rr < 16; rr++) { float v = zb[rr * 16 + cl]; sm += v; sq += v * v; }
    float mean = sm * (1.f / 16.f);
    float var = sq * (1.f / 16.f) - mean * mean;
    float h = gm1[c] * (z - mean) * rsqrtf(var + 1e-5f) + betam1[c];
    hbuf[(size_t)r * 512 + c] = h > 0.f ? h : 0.2f * h;
}

// ---------------------------------------------------------------- MLP stage 2
__global__ void k_mlp2(const float* __restrict__ hbuf, const float* __restrict__ Wm2,
                       const float* __restrict__ bm2, float* __restrict__ out) {
    int gid = blockIdx.x * 256 + threadIdx.x;
    if (gid >= 640) return;
    int r = gid / 40, c = gid % 40;
    float o = bm2[c];
    const float* hr = hbuf + (size_t)r * 512;
    for (int kk = 0; kk < 512; kk++) o += hr[kk] * Wm2[(size_t)kk * 40 + c];
    out[gid] = o;
}

// ----------------------------------------------------------------
extern "C" void kernel_launch(void* const* d_in, const int* in_sizes, int n_in,
                              void* d_out, int out_size, void* d_ws, size_t ws_size,
                              hipStream_t stream) {
    const float* pos = (const float*)d_in[0];
    const float* W1 = (const float*)d_in[2];
    const float* b1 = (const float*)d_in[3];
    const float* W2 = (const float*)d_in[4];
    const float* b2 = (const float*)d_in[5];
    const float* W3 = (const float*)d_in[6];
    const float* b3 = (const float*)d_in[7];
    const float* W4 = (const float*)d_in[8];
    const float* b4 = (const float*)d_in[9];
    const float* Wl = (const float*)d_in[10];
    const float* bl = (const float*)d_in[11];
    const float* gl = (const float*)d_in[12];
    const float* betal = (const float*)d_in[13];
    const float* Wm1 = (const float*)d_in[14];
    const float* bm1 = (const float*)d_in[15];
    const float* gm1 = (const float*)d_in[16];
    const float* betam1 = (const float*)d_in[17];
    const float* Wm2 = (const float*)d_in[18];
    const float* bm2 = (const float*)d_in[19];
    float* out = (float*)d_out;

    float* ws = (float*)d_ws;
    float* cat_ = ws;                                   // 16384*512
    float* pq = cat_ + (size_t)NROW * 512;              // 16384*512
    int* idx = (int*)(pq + (size_t)NROW * 512);         // 16384*20
    float* sqb = (float*)(idx + NROW * 20);             // 16384
    float* wc1 = sqb + NROW;
    float* wc2 = wc1 + 3 * 128;
    float* wc3 = wc2 + 64 * 128;
    float* wc4 = wc3 + 64 * 256;
    float* bb1 = wc4 + 128 * 512;
    float* bb2 = bb1 + 128;
    float* bb3 = bb2 + 128;
    float* bb4 = bb3 + 256;
    float* colsum = bb4 + 512;
    float* colsq = colsum + 1024;
    float* pmax = colsq + 1024;                         // 4*16384
    float* pmin = pmax + 4 * NROW;                      // 4*16384
    float* pooled = pmin + 4 * NROW;                    // 16384
    float* hbuf = pooled + NROW;                        // 8192
    size_t need = (size_t)((hbuf + 16 * 512) - ws) * sizeof(float);
    if (ws_size < need) return;

    // kNN candidate buffer aliases pq (pq is written only after merge completes, stream-ordered)
    unsigned long long* cand = (unsigned long long*)pq; // 16384*80 u64 = 10.5MB < 32MB

    k_init<<<256, 256, 0, stream>>>(colsum, colsq, pmax, pmin);
    k_prep<<<256, 256, 0, stream>>>(W1, b1, wc1, bb1, 3, 64);
    k_prep<<<256, 256, 0, stream>>>(W2, b2, wc2, bb2, 64, 64);
    k_prep<<<256, 256, 0, stream>>>(W3, b3, wc3, bb3, 64, 128);
    k_prep<<<256, 256, 0, stream>>>(W4, b4, wc4, bb4, 128, 256);

    // layer 1 (D=3 -> 64)
    k_sqnorm<<<4096, 256, 0, stream>>>(pos, 3, 3, sqb);
    k_knn_scan<3><<<dim3(16, 16, NCH), 256, 0, stream>>>(pos, 3, sqb, cand);
    k_knn_merge<<<64, 256, 0, stream>>>(cand, idx);
    k_gemm_pq<3, 64><<<dim3(256, 2), 256, 0, stream>>>(pos, 3, wc1, bb1, pq);
    k_gather<<<4096, 256, 0, stream>>>(pq, idx, cat_, 6, 0);
    // layer 2 (64 -> 64)
    k_sqnorm<<<4096, 256, 0, stream>>>(cat_, 512, 64, sqb);
    k_knn_scan<64><<<dim3(16, 16, NCH), 256, 0, stream>>>(cat_, 512, sqb, cand);
    k_knn_merge<<<64, 256, 0, stream>>>(cand, idx);
    k_gemm_pq<64, 64><<<dim3(256, 2), 256, 0, stream>>>(cat_, 512, wc2, bb2, pq);
    k_gather<<<4096, 256, 0, stream>>>(pq, idx, cat_, 6, 64);
    // layer 3 (64 -> 128)
    k_sqnorm<<<4096, 256, 0, stream>>>(cat_ + 64, 512, 64, sqb);
    k_knn_scan<64><<<dim3(16, 16, NCH), 256, 0, stream>>>(cat_ + 64, 512, sqb, cand);
    k_knn_merge<<<64, 256, 0, stream>>>(cand, idx);
    k_gemm_pq<64, 128><<<dim3(256, 4), 256, 0, stream>>>(cat_ + 64, 512, wc3, bb3, pq);
    k_gather<<<8192, 256, 0, stream>>>(pq, idx, cat_, 7, 128);
    // layer 4 (128 -> 256)
    k_sqnorm<<<4096, 256, 0, stream>>>(cat_ + 128, 512, 128, sqb);
    k_knn_scan<128><<<dim3(16, 16, NCH), 256, 0, stream>>>(cat_ + 128, 512, sqb, cand);
    k_knn_merge<<<64, 256, 0, stream>>>(cand, idx);
    k_gemm_pq<128, 256><<<dim3(256, 8), 256, 0, stream>>>(cat_ + 128, 512, wc4, bb4, pq);
    k_gather<<<16384, 256, 0, stream>>>(pq, idx, cat_, 8, 256);

    k_fused_lin<<<dim3(16, 16, 4), 256, 0, stream>>>(cat_, Wl, bl, colsum, colsq, pmax, pmin);
    k_bnpool<<<64, 256, 0, stream>>>(colsum, colsq, pmax, pmin, gl, betal, pooled);
    k_mlp1<<<32, 256, 0, stream>>>(pooled, Wm1, bm1, gm1, betam1, hbuf);
    k_mlp2<<<3, 256, 0, stream>>>(hbuf, Wm2, bm2, out);
}

// Round 10
// 1040.234 us; speedup vs baseline: 1.5344x; 1.5344x over previous
//
#include <hip/hip_runtime.h>
#include <float.h>

#define NB 16
#define NP 1024
#define NROW (NB*NP)

// ---------------------------------------------------------------- init
__global__ void k_init(float* colsum, float* colsq, float* pmax, float* pmin) {
    int i = blockIdx.x * 256 + threadIdx.x;          // grid 256 -> i < 65536
    if (i < 1024) { colsum[i] = 0.f; colsq[i] = 0.f; }
    pmax[i] = -FLT_MAX;
    pmin[i] =  FLT_MAX;
}

// ---------------------------------------------------------------- weight prep
__global__ void k_prep(const float* __restrict__ W, const float* __restrict__ b,
                       float* __restrict__ wc, float* __restrict__ b2, int d, int dout) {
    int n2 = 2 * dout;
    int i = blockIdx.x * 256 + threadIdx.x;
    if (i < d * n2) {
        int kk = i / n2, c = i % n2;
        wc[i] = (c < dout) ? (W[kk * dout + c] - W[(kk + d) * dout + c])
                           : W[(kk + d) * dout + (c - dout)];
    }
    if (i < n2) b2[i] = (i < dout) ? b[i] : 0.f;
}

// ---------------------------------------------------------------- squared norms
__global__ void k_sqnorm(const float* __restrict__ x, int stride, int D, float* __restrict__ sq) {
    int row = blockIdx.x * 4 + (threadIdx.x >> 6);
    int lane = threadIdx.x & 63;
    const float* xr = x + (size_t)row * stride;
    float s = 0.f;
    for (int kk = lane; kk < D; kk += 64) { float v = xr[kk]; s += v * v; }
    for (int o = 32; o; o >>= 1) s += __shfl_down(s, o);
    if (lane == 0) sq[row] = s;
}

// ---------------------------------------------------------------- float -> order-preserving u32
__device__ inline unsigned ford(float f) {
    unsigned u = __float_as_uint(f);
    return (u & 0x80000000u) ? ~u : (u | 0x80000000u);
}

#define FMA16(a, bv) do { \
    acc[0].x += (a).x*(bv).x; acc[0].y += (a).x*(bv).y; acc[0].z += (a).x*(bv).z; acc[0].w += (a).x*(bv).w; \
    acc[1].x += (a).y*(bv).x; acc[1].y += (a).y*(bv).y; acc[1].z += (a).y*(bv).z; acc[1].w += (a).y*(bv).w; \
    acc[2].x += (a).z*(bv).x; acc[2].y += (a).z*(bv).y; acc[2].z += (a).z*(bv).z; acc[2].w += (a).z*(bv).w; \
    acc[3].x += (a).w*(bv).x; acc[3].y += (a).w*(bv).y; acc[3].z += (a).w*(bv).z; acc[3].w += (a).w*(bv).w; \
} while (0)

// ---------------------------------------------------------------- distance tile GEMM: dist[r][j] = sq[j] - 2 * x_r . x_j
// grid (j-tiles 16, row-tiles 16, 8 clouds-per-pass), block 256, 4x4 per thread.
template<int D>
__global__ __launch_bounds__(256) void k_dist(const float* __restrict__ x, int stride,
                                              const float* __restrict__ sq,
                                              float* __restrict__ dist, int pass) {
    constexpr int KC = (D > 64) ? 64 : D;
    __shared__ __align__(16) float At[KC * 68];
    __shared__ __align__(16) float Bt[KC * 64];
    const int tid = threadIdx.x;
    const int tx = tid & 15, ty = tid >> 4;
    const int j0 = blockIdx.x * 64;
    const int r0 = blockIdx.y * 64;
    const int c8 = blockIdx.z;
    const int bb = pass * 8 + c8;

    float4 acc[4] = {};
    for (int k0 = 0; k0 < D; k0 += KC) {
        __syncthreads();
        if constexpr (KC % 4 == 0) {
            constexpr int K4 = KC / 4;
            for (int e = tid; e < 64 * K4; e += 256) {
                int rr = e / K4, kq = e % K4;
                float4 v = *(const float4*)(x + (size_t)(bb * NP + r0 + rr) * stride + k0 + kq * 4);
                At[(4 * kq + 0) * 68 + rr] = v.x;
                At[(4 * kq + 1) * 68 + rr] = v.y;
                At[(4 * kq + 2) * 68 + rr] = v.z;
                At[(4 * kq + 3) * 68 + rr] = v.w;
            }
            for (int e = tid; e < 64 * K4; e += 256) {
                int jj = e / K4, kq = e % K4;
                float4 v = *(const float4*)(x + (size_t)(bb * NP + j0 + jj) * stride + k0 + kq * 4);
                Bt[(4 * kq + 0) * 64 + jj] = v.x;
                Bt[(4 * kq + 1) * 64 + jj] = v.y;
                Bt[(4 * kq + 2) * 64 + jj] = v.z;
                Bt[(4 * kq + 3) * 64 + jj] = v.w;
            }
        } else {
            for (int e = tid; e < 64 * KC; e += 256) {
                int rr = e / KC, kk = e % KC;
                At[kk * 68 + rr] = x[(size_t)(bb * NP + r0 + rr) * stride + k0 + kk];
            }
            for (int e = tid; e < 64 * KC; e += 256) {
                int jj = e / KC, kk = e % KC;
                Bt[kk * 64 + jj] = x[(size_t)(bb * NP + j0 + jj) * stride + k0 + kk];
            }
        }
        __syncthreads();
#pragma unroll 8
        for (int kk = 0; kk < KC; kk++) {
            float4 a = *(const float4*)&At[kk * 68 + ty * 4];
            float4 bv = *(const float4*)&Bt[kk * 64 + tx * 4];
            FMA16(a, bv);
        }
    }
    float4 sqv = *(const float4*)(sq + bb * NP + j0 + tx * 4);
#pragma unroll
    for (int ri = 0; ri < 4; ri++) {
        float4 o;
        o.x = sqv.x - 2.f * acc[ri].x;
        o.y = sqv.y - 2.f * acc[ri].y;
        o.z = sqv.z - 2.f * acc[ri].z;
        o.w = sqv.w - 2.f * acc[ri].w;
        *(float4*)(dist + (size_t)(c8 * NP + r0 + ty * 4 + ri) * NP + j0 + tx * 4) = o;
    }
}

// ---------------------------------------------------------------- top-20 select: one wave per row
// dist row (1024) -> 16 packed u64 per lane -> 20x (masked reg-scan + butterfly min)
__global__ __launch_bounds__(256) void k_select(const float* __restrict__ dist,
                                                int* __restrict__ idxout, int pass) {
    const int w = threadIdx.x >> 6, lane = threadIdx.x & 63;
    const int rowlocal = blockIdx.x * 4 + w;          // 0..8191 per pass
    const size_t base = (size_t)rowlocal * NP;
    const int growrow = pass * 8 * NP + rowlocal;     // global row

    unsigned long long pk[16];
    const float4* dp = (const float4*)(dist + base + lane * 16);
#pragma unroll
    for (int q = 0; q < 4; q++) {
        float4 v = dp[q];
        int jb = lane * 16 + q * 4;
        pk[q * 4 + 0] = ((unsigned long long)ford(v.x) << 32) | (unsigned)(jb + 0);
        pk[q * 4 + 1] = ((unsigned long long)ford(v.y) << 32) | (unsigned)(jb + 1);
        pk[q * 4 + 2] = ((unsigned long long)ford(v.z) << 32) | (unsigned)(jb + 2);
        pk[q * 4 + 3] = ((unsigned long long)ford(v.w) << 32) | (unsigned)(jb + 3);
    }
    unsigned msk = 0;
#pragma unroll 1
    for (int it = 0; it < 20; it++) {
        unsigned long long m = 0xFFFFFFFFFFFFFFFFULL;
#pragma unroll
        for (int t = 0; t < 16; t++) {
            unsigned long long v = (msk & (1u << t)) ? 0xFFFFFFFFFFFFFFFFULL : pk[t];
            m = (v < m) ? v : m;
        }
#pragma unroll
        for (int o = 32; o; o >>= 1) {
            unsigned long long v = __shfl_xor(m, o);
            m = (v < m) ? v : m;
        }
        unsigned wj = (unsigned)(m & 0xFFFFFFFFu);
        if (lane == (int)(wj >> 4)) msk |= 1u << (wj & 15u);
        if (lane == 0) idxout[(size_t)growrow * 20 + it] = (int)wj;
    }
}

// ---------------------------------------------------------------- p/q GEMM:  pq = x @ wc + b2
template<int D, int DOUT>
__global__ __launch_bounds__(256) void k_gemm_pq(const float* __restrict__ x, int stride,
                                                 const float* __restrict__ wc, const float* __restrict__ b2,
                                                 float* __restrict__ pq) {
    constexpr int N2 = 2 * DOUT;
    constexpr int KC = (D > 64) ? 64 : D;
    __shared__ __align__(16) float At[KC * 68];
    __shared__ __align__(16) float Bs[KC * 64];
    const int tid = threadIdx.x;
    const int tx = tid & 15, ty = tid >> 4;
    const int r0 = blockIdx.x * 64;
    const int c0 = blockIdx.y * 64;

    float4 acc[4] = {};
    for (int k0 = 0; k0 < D; k0 += KC) {
        __syncthreads();
        if constexpr (KC % 4 == 0) {
            constexpr int K4 = KC / 4;
            for (int e = tid; e < 64 * K4; e += 256) {
                int rr = e / K4, kq = e % K4;
                float4 v = *(const float4*)(x + (size_t)(r0 + rr) * stride + k0 + kq * 4);
                At[(4 * kq + 0) * 68 + rr] = v.x;
                At[(4 * kq + 1) * 68 + rr] = v.y;
                At[(4 * kq + 2) * 68 + rr] = v.z;
                At[(4 * kq + 3) * 68 + rr] = v.w;
            }
        } else {
            for (int e = tid; e < 64 * KC; e += 256) {
                int rr = e / KC, kk = e % KC;
                At[kk * 68 + rr] = x[(size_t)(r0 + rr) * stride + k0 + kk];
            }
        }
        for (int e = tid; e < KC * 16; e += 256) {
            int kk = e / 16, cq = e % 16;
            *(float4*)&Bs[kk * 64 + cq * 4] = *(const float4*)(wc + (size_t)(k0 + kk) * N2 + c0 + cq * 4);
        }
        __syncthreads();
#pragma unroll 8
        for (int kk = 0; kk < KC; kk++) {
            float4 a = *(const float4*)&At[kk * 68 + ty * 4];
            float4 bv = *(const float4*)&Bs[kk * 64 + tx * 4];
            FMA16(a, bv);
        }
    }
    float4 bias = *(const float4*)(b2 + c0 + tx * 4);
#pragma unroll
    for (int ri = 0; ri < 4; ri++) {
        float4 o;
        o.x = acc[ri].x + bias.x; o.y = acc[ri].y + bias.y;
        o.z = acc[ri].z + bias.z; o.w = acc[ri].w + bias.w;
        *(float4*)(pq + (size_t)(r0 + ty * 4 + ri) * N2 + c0 + tx * 4) = o;
    }
}

// ---------------------------------------------------------------- gather + max over 20 neighbors
__global__ void k_gather(const float* __restrict__ pq, const int* __restrict__ idx,
                         float* __restrict__ cat_, int log2dout, int off) {
    int gid = blockIdx.x * 256 + threadIdx.x;
    int dout = 1 << log2dout;
    int row = gid >> log2dout;
    int c = gid & (dout - 1);
    int b = row >> 10;
    int s2 = dout * 2;
    const float* qb = pq + (size_t)(b << 10) * s2 + dout + c;
    const int* ip = idx + (size_t)row * 20;
    float m = -FLT_MAX;
#pragma unroll
    for (int t = 0; t < 20; t++) {
        int j = ip[t];
        m = fmaxf(m, qb[(size_t)j * s2]);
    }
    cat_[(size_t)row * 512 + off + c] = pq[(size_t)row * s2 + c] + m;
}

// ---------------------------------------------------------------- fused linear: y = cat@Wl + bl, col stats + per-(b,c) max/min
__global__ __launch_bounds__(256) void k_fused_lin(const float* __restrict__ cat_, const float* __restrict__ Wl,
                                                   const float* __restrict__ bl,
                                                   float* colsum, float* colsq, float* pmax, float* pmin) {
    __shared__ __align__(16) float At[32 * 68];
    __shared__ __align__(16) float Bs[32 * 64];
    __shared__ float red[16 * 64];
    const int tid = threadIdx.x;
    const int tx = tid & 15, ty = tid >> 4;
    const int ct = blockIdx.x, b = blockIdx.y, rs = blockIdx.z;
    const int c0 = ct * 64;

    float4 blv = *(const float4*)(bl + c0 + tx * 4);
    float4 s = {0, 0, 0, 0}, ss = {0, 0, 0, 0};
    float4 mx = {-FLT_MAX, -FLT_MAX, -FLT_MAX, -FLT_MAX};
    float4 mn = {FLT_MAX, FLT_MAX, FLT_MAX, FLT_MAX};

    for (int rt = 0; rt < 4; rt++) {
        int r0 = b * 1024 + rs * 256 + rt * 64;
        float4 acc[4] = {};
        for (int kt = 0; kt < 16; kt++) {
            __syncthreads();
            for (int e = tid; e < 512; e += 256) {
                int rr = e >> 3, kq = e & 7;
                float4 v = *(const float4*)(cat_ + (size_t)(r0 + rr) * 512 + kt * 32 + kq * 4);
                At[(4 * kq + 0) * 68 + rr] = v.x;
                At[(4 * kq + 1) * 68 + rr] = v.y;
                At[(4 * kq + 2) * 68 + rr] = v.z;
                At[(4 * kq + 3) * 68 + rr] = v.w;
            }
            for (int e = tid; e < 512; e += 256) {
                int kk = e >> 4, cq = e & 15;
                *(float4*)&Bs[kk * 64 + cq * 4] = *(const float4*)(Wl + (size_t)(kt * 32 + kk) * 1024 + c0 + cq * 4);
            }
            __syncthreads();
#pragma unroll 8
            for (int kk = 0; kk < 32; kk++) {
                float4 a = *(const float4*)&At[kk * 68 + ty * 4];
                float4 bv = *(const float4*)&Bs[kk * 64 + tx * 4];
                FMA16(a, bv);
            }
        }
#pragma unroll
        for (int ri = 0; ri < 4; ri++) {
            float yx = acc[ri].x + blv.x, yy = acc[ri].y + blv.y;
            float yz = acc[ri].z + blv.z, yw = acc[ri].w + blv.w;
            s.x += yx; ss.x += yx * yx; mx.x = fmaxf(mx.x, yx); mn.x = fminf(mn.x, yx);
            s.y += yy; ss.y += yy * yy; mx.y = fmaxf(mx.y, yy); mn.y = fminf(mn.y, yy);
            s.z += yz; ss.z += yz * yz; mx.z = fmaxf(mx.z, yz); mn.z = fminf(mn.z, yz);
            s.w += yw; ss.w += yw * yw; mx.w = fmaxf(mx.w, yw); mn.w = fminf(mn.w, yw);
        }
    }

    float rsum = 0.f, rss = 0.f, rmx = -FLT_MAX, rmn = FLT_MAX;
    __syncthreads(); *(float4*)&red[ty * 64 + tx * 4] = s;  __syncthreads();
    if (tid < 64) for (int t = 0; t < 16; t++) rsum += red[t * 64 + tid];
    __syncthreads(); *(float4*)&red[ty * 64 + tx * 4] = ss; __syncthreads();
    if (tid < 64) for (int t = 0; t < 16; t++) rss += red[t * 64 + tid];
    __syncthreads(); *(float4*)&red[ty * 64 + tx * 4] = mx; __syncthreads();
    if (tid < 64) for (int t = 0; t < 16; t++) rmx = fmaxf(rmx, red[t * 64 + tid]);
    __syncthreads(); *(float4*)&red[ty * 64 + tx * 4] = mn; __syncthreads();
    if (tid < 64) for (int t = 0; t < 16; t++) rmn = fminf(rmn, red[t * 64 + tid]);

    if (tid < 64) {
        int c = c0 + tid;
        atomicAdd(&colsum[c], rsum);
        atomicAdd(&colsq[c], rss);
        pmax[(size_t)(rs * 16 + b) * 1024 + c] = rmx;
        pmin[(size_t)(rs * 16 + b) * 1024 + c] = rmn;
    }
}

// ---------------------------------------------------------------- BN + leaky + pool (commuted through max/min)
__global__ void k_bnpool(const float* colsum, const float* colsq,
                         const float* pmax, const float* pmin,
                         const float* __restrict__ gl, const float* __restrict__ betal,
                         float* __restrict__ pooled) {
    int gid = blockIdx.x * 256 + threadIdx.x;   // 16384
    int c = gid & 1023, b = gid >> 10;
    float mean = colsum[c] * (1.f / 16384.f);
    float var = colsq[c] * (1.f / 16384.f) - mean * mean;
    float a = gl[c] * rsqrtf(var + 1e-5f);
    float d = betal[c] - mean * a;
    float vmx = -FLT_MAX, vmn = FLT_MAX;
#pragma unroll
    for (int rs = 0; rs < 4; rs++) {
        vmx = fmaxf(vmx, pmax[(size_t)(rs * 16 + b) * 1024 + c]);
        vmn = fminf(vmn, pmin[(size_t)(rs * 16 + b) * 1024 + c]);
    }
    float v = a * ((a >= 0.f) ? vmx : vmn) + d;
    pooled[gid] = v > 0.f ? v : 0.2f * v;
}

// ---------------------------------------------------------------- MLP stage 1
__global__ __launch_bounds__(256) void k_mlp1(const float* __restrict__ pooled, const float* __restrict__ Wm1,
                                              const float* __restrict__ bm1, const float* __restrict__ gm1,
                                              const float* __restrict__ betam1, float* __restrict__ hbuf) {
    int tid = threadIdx.x;
    int r = tid >> 4, cl = tid & 15;
    int c = blockIdx.x * 16 + cl;
    float z = bm1[c];
    const float* pr = pooled + (size_t)r * 1024;
    for (int kk = 0; kk < 1024; kk++) z += pr[kk] * Wm1[(size_t)kk * 512 + c];
    __shared__ float zb[16 * 16];
    zb[r * 16 + cl] = z;
    __syncthreads();
    float sm = 0.f, sq = 0.f;
#pragma unroll
    for (int rr = 0; rr < 16; rr++) { float v = zb[rr * 16 + cl]; sm += v; sq += v * v; }
    float mean = sm * (1.f / 16.f);
    float var = sq * (1.f / 16.f) - mean * mean;
    float h = gm1[c] * (z - mean) * rsqrtf(var + 1e-5f) + betam1[c];
    hbuf[(size_t)r * 512 + c] = h > 0.f ? h : 0.2f * h;
}

// ---------------------------------------------------------------- MLP stage 2
__global__ void k_mlp2(const float* __restrict__ hbuf, const float* __restrict__ Wm2,
                       const float* __restrict__ bm2, float* __restrict__ out) {
    int gid = blockIdx.x * 256 + threadIdx.x;
    if (gid >= 640) return;
    int r = gid / 40, c = gid % 40;
    float o = bm2[c];
    const float* hr = hbuf + (size_t)r * 512;
    for (int kk = 0; kk < 512; kk++) o += hr[kk] * Wm2[(size_t)kk * 40 + c];
    out[gid] = o;
}

// ----------------------------------------------------------------
extern "C" void kernel_launch(void* const* d_in, const int* in_sizes, int n_in,
                              void* d_out, int out_size, void* d_ws, size_t ws_size,
                              hipStream_t stream) {
    const float* pos = (const float*)d_in[0];
    const float* W1 = (const float*)d_in[2];
    const float* b1 = (const float*)d_in[3];
    const float* W2 = (const float*)d_in[4];
    const float* b2 = (const float*)d_in[5];
    const float* W3 = (const float*)d_in[6];
    const float* b3 = (const float*)d_in[7];
    const float* W4 = (const float*)d_in[8];
    const float* b4 = (const float*)d_in[9];
    const float* Wl = (const float*)d_in[10];
    const float* bl = (const float*)d_in[11];
    const float* gl = (const float*)d_in[12];
    const float* betal = (const float*)d_in[13];
    const float* Wm1 = (const float*)d_in[14];
    const float* bm1 = (const float*)d_in[15];
    const float* gm1 = (const float*)d_in[16];
    const float* betam1 = (const float*)d_in[17];
    const float* Wm2 = (const float*)d_in[18];
    const float* bm2 = (const float*)d_in[19];
    float* out = (float*)d_out;

    float* ws = (float*)d_ws;
    float* cat_ = ws;                                   // 16384*512
    float* pq = cat_ + (size_t)NROW * 512;              // 16384*512 (aliased by dist during kNN)
    int* idx = (int*)(pq + (size_t)NROW * 512);         // 16384*20
    float* sqb = (float*)(idx + NROW * 20);             // 16384
    float* wc1 = sqb + NROW;
    float* wc2 = wc1 + 3 * 128;
    float* wc3 = wc2 + 64 * 128;
    float* wc4 = wc3 + 64 * 256;
    float* bb1 = wc4 + 128 * 512;
    float* bb2 = bb1 + 128;
    float* bb3 = bb2 + 128;
    float* bb4 = bb3 + 256;
    float* colsum = bb4 + 512;
    float* colsq = colsum + 1024;
    float* pmax = colsq + 1024;                         // 4*16384
    float* pmin = pmax + 4 * NROW;                      // 4*16384
    float* pooled = pmin + 4 * NROW;                    // 16384
    float* hbuf = pooled + NROW;                        // 8192
    size_t need = (size_t)((hbuf + 16 * 512) - ws) * sizeof(float);
    if (ws_size < need) return;

    float* dist = pq;   // 8*1024*1024 floats = exactly the pq region; pq written after select

    k_init<<<256, 256, 0, stream>>>(colsum, colsq, pmax, pmin);
    k_prep<<<256, 256, 0, stream>>>(W1, b1, wc1, bb1, 3, 64);
    k_prep<<<256, 256, 0, stream>>>(W2, b2, wc2, bb2, 64, 64);
    k_prep<<<256, 256, 0, stream>>>(W3, b3, wc3, bb3, 64, 128);
    k_prep<<<256, 256, 0, stream>>>(W4, b4, wc4, bb4, 128, 256);

    // layer 1 (D=3 -> 64)
    k_sqnorm<<<4096, 256, 0, stream>>>(pos, 3, 3, sqb);
    for (int p = 0; p < 2; p++) {
        k_dist<3><<<dim3(16, 16, 8), 256, 0, stream>>>(pos, 3, sqb, dist, p);
        k_select<<<2048, 256, 0, stream>>>(dist, idx, p);
    }
    k_gemm_pq<3, 64><<<dim3(256, 2), 256, 0, stream>>>(pos, 3, wc1, bb1, pq);
    k_gather<<<4096, 256, 0, stream>>>(pq, idx, cat_, 6, 0);
    // layer 2 (64 -> 64)
    k_sqnorm<<<4096, 256, 0, stream>>>(cat_, 512, 64, sqb);
    for (int p = 0; p < 2; p++) {
        k_dist<64><<<dim3(16, 16, 8), 256, 0, stream>>>(cat_, 512, sqb, dist, p);
        k_select<<<2048, 256, 0, stream>>>(dist, idx, p);
    }
    k_gemm_pq<64, 64><<<dim3(256, 2), 256, 0, stream>>>(cat_, 512, wc2, bb2, pq);
    k_gather<<<4096, 256, 0, stream>>>(pq, idx, cat_, 6, 64);
    // layer 3 (64 -> 128)
    k_sqnorm<<<4096, 256, 0, stream>>>(cat_ + 64, 512, 64, sqb);
    for (int p = 0; p < 2; p++) {
        k_dist<64><<<dim3(16, 16, 8), 256, 0, stream>>>(cat_ + 64, 512, sqb, dist, p);
        k_select<<<2048, 256, 0, stream>>>(dist, idx, p);
    }
    k_gemm_pq<64, 128><<<dim3(256, 4), 256, 0, stream>>>(cat_ + 64, 512, wc3, bb3, pq);
    k_gather<<<8192, 256, 0, stream>>>(pq, idx, cat_, 7, 128);
    // layer 4 (128 -> 256)
    k_sqnorm<<<4096, 256, 0, stream>>>(cat_ + 128, 512, 128, sqb);
    for (int p = 0; p < 2; p++) {
        k_dist<128><<<dim3(16, 16, 8), 256, 0, stream>>>(cat_ + 128, 512, sqb, dist, p);
        k_select<<<2048, 256, 0, stream>>>(dist, idx, p);
    }
    k_gemm_pq<128, 256><<<dim3(256, 8), 256, 0, stream>>>(cat_ + 128, 512, wc4, bb4, pq);
    k_gather<<<16384, 256, 0, stream>>>(pq, idx, cat_, 8, 256);

    k_fused_lin<<<dim3(16, 16, 4), 256, 0, stream>>>(cat_, Wl, bl, colsum, colsq, pmax, pmin);
    k_bnpool<<<64, 256, 0, stream>>>(colsum, colsq, pmax, pmin, gl, betal, pooled);
    k_mlp1<<<32, 256, 0, stream>>>(pooled, Wm1, bm1, gm1, betam1, hbuf);
    k_mlp2<<<3, 256, 0, stream>>>(hbuf, Wm2, bm2, out);
}

// Round 12
// 967.483 us; speedup vs baseline: 1.6498x; 1.0752x over previous
//
#include <hip/hip_runtime.h>
#include <float.h>

#define NB 16
#define NP 1024
#define NROW (NB*NP)

// ---------------------------------------------------------------- init (stats+pool buffers; pmax/pmin alias pq, init AFTER gather L4)
__global__ void k_init(float* colsum, float* colsq, float* pmax, float* pmin) {
    int i = blockIdx.x * 256 + threadIdx.x;          // grid 512 -> i < 131072
    if (i < 1024) { colsum[i] = 0.f; colsq[i] = 0.f; }
    pmax[i] = -FLT_MAX;
    pmin[i] =  FLT_MAX;
}

// ---------------------------------------------------------------- weight prep
__global__ void k_prep(const float* __restrict__ W, const float* __restrict__ b,
                       float* __restrict__ wc, float* __restrict__ b2, int d, int dout) {
    int n2 = 2 * dout;
    int i = blockIdx.x * 256 + threadIdx.x;
    if (i < d * n2) {
        int kk = i / n2, c = i % n2;
        wc[i] = (c < dout) ? (W[kk * dout + c] - W[(kk + d) * dout + c])
                           : W[(kk + d) * dout + (c - dout)];
    }
    if (i < n2) b2[i] = (i < dout) ? b[i] : 0.f;
}

// ---------------------------------------------------------------- squared norms
__global__ void k_sqnorm(const float* __restrict__ x, int stride, int D, float* __restrict__ sq) {
    int row = blockIdx.x * 4 + (threadIdx.x >> 6);
    int lane = threadIdx.x & 63;
    const float* xr = x + (size_t)row * stride;
    float s = 0.f;
    for (int kk = lane; kk < D; kk += 64) { float v = xr[kk]; s += v * v; }
    for (int o = 32; o; o >>= 1) s += __shfl_down(s, o);
    if (lane == 0) sq[row] = s;
}

// ---------------------------------------------------------------- float -> order-preserving u32
__device__ inline unsigned ford(float f) {
    unsigned u = __float_as_uint(f);
    return (u & 0x80000000u) ? ~u : (u | 0x80000000u);
}

// 8 FMAs: c0/c1 (float4 pair) += s * (b0,b1)
#define FMA8(c0_, c1_, s_, b0_, b1_) do { \
    (c0_).x += (s_)*(b0_).x; (c0_).y += (s_)*(b0_).y; (c0_).z += (s_)*(b0_).z; (c0_).w += (s_)*(b0_).w; \
    (c1_).x += (s_)*(b1_).x; (c1_).y += (s_)*(b1_).y; (c1_).z += (s_)*(b1_).z; (c1_).w += (s_)*(b1_).w; \
} while (0)

#define FMA16(a, bv) do { \
    acc[0].x += (a).x*(bv).x; acc[0].y += (a).x*(bv).y; acc[0].z += (a).x*(bv).z; acc[0].w += (a).x*(bv).w; \
    acc[1].x += (a).y*(bv).x; acc[1].y += (a).y*(bv).y; acc[1].z += (a).y*(bv).z; acc[1].w += (a).y*(bv).w; \
    acc[2].x += (a).z*(bv).x; acc[2].y += (a).z*(bv).y; acc[2].z += (a).z*(bv).z; acc[2].w += (a).z*(bv).w; \
    acc[3].x += (a).w*(bv).x; acc[3].y += (a).w*(bv).y; acc[3].z += (a).w*(bv).z; acc[3].w += (a).w*(bv).w; \
} while (0)

// ---------------------------------------------------------------- distance tile GEMM, 128x128 tile, 8x8/thread
// dist[r][j] = sq[j] - 2 * x_r . x_j ; grid (8 j-tiles, 8 row-tiles, 8 clouds), block 256.
template<int D>
__global__ __launch_bounds__(256) void k_dist(const float* __restrict__ x, int stride,
                                              const float* __restrict__ sq,
                                              float* __restrict__ dist, int pass) {
    constexpr int KC = (D < 32) ? D : 32;
    __shared__ __align__(16) float At[KC * 132];
    __shared__ __align__(16) float Bt[KC * 132];
    const int tid = threadIdx.x;
    const int tx = tid & 15, ty = tid >> 4;
    const int j0 = blockIdx.x * 128;
    const int r0 = blockIdx.y * 128;
    const int bb = pass * 8 + blockIdx.z;

    float4 acc0[8] = {}, acc1[8] = {};
    for (int k0 = 0; k0 < D; k0 += KC) {
        __syncthreads();
        if constexpr (KC % 4 == 0) {
            constexpr int K4 = KC / 4;
            for (int e = tid; e < 128 * K4; e += 256) {
                int rr = e / K4, kq = e % K4;
                float4 v = *(const float4*)(x + (size_t)(bb * NP + r0 + rr) * stride + k0 + kq * 4);
                At[(4 * kq + 0) * 132 + rr] = v.x;
                At[(4 * kq + 1) * 132 + rr] = v.y;
                At[(4 * kq + 2) * 132 + rr] = v.z;
                At[(4 * kq + 3) * 132 + rr] = v.w;
            }
            for (int e = tid; e < 128 * K4; e += 256) {
                int jj = e / K4, kq = e % K4;
                float4 v = *(const float4*)(x + (size_t)(bb * NP + j0 + jj) * stride + k0 + kq * 4);
                Bt[(4 * kq + 0) * 132 + jj] = v.x;
                Bt[(4 * kq + 1) * 132 + jj] = v.y;
                Bt[(4 * kq + 2) * 132 + jj] = v.z;
                Bt[(4 * kq + 3) * 132 + jj] = v.w;
            }
        } else {
            for (int e = tid; e < 128 * KC; e += 256) {
                int rr = e / KC, kk = e % KC;
                At[kk * 132 + rr] = x[(size_t)(bb * NP + r0 + rr) * stride + k0 + kk];
            }
            for (int e = tid; e < 128 * KC; e += 256) {
                int jj = e / KC, kk = e % KC;
                Bt[kk * 132 + jj] = x[(size_t)(bb * NP + j0 + jj) * stride + k0 + kk];
            }
        }
        __syncthreads();
#pragma unroll 4
        for (int kk = 0; kk < KC; kk++) {
            float4 a0 = *(const float4*)&At[kk * 132 + ty * 8];
            float4 a1 = *(const float4*)&At[kk * 132 + ty * 8 + 4];
            float4 b0 = *(const float4*)&Bt[kk * 132 + tx * 8];
            float4 b1 = *(const float4*)&Bt[kk * 132 + tx * 8 + 4];
            FMA8(acc0[0], acc1[0], a0.x, b0, b1);
            FMA8(acc0[1], acc1[1], a0.y, b0, b1);
            FMA8(acc0[2], acc1[2], a0.z, b0, b1);
            FMA8(acc0[3], acc1[3], a0.w, b0, b1);
            FMA8(acc0[4], acc1[4], a1.x, b0, b1);
            FMA8(acc0[5], acc1[5], a1.y, b0, b1);
            FMA8(acc0[6], acc1[6], a1.z, b0, b1);
            FMA8(acc0[7], acc1[7], a1.w, b0, b1);
        }
    }
    float4 sq0 = *(const float4*)(sq + bb * NP + j0 + tx * 8);
    float4 sq1 = *(const float4*)(sq + bb * NP + j0 + tx * 8 + 4);
#pragma unroll
    for (int ri = 0; ri < 8; ri++) {
        float* dp = dist + (size_t)(blockIdx.z * NP + r0 + ty * 8 + ri) * NP + j0 + tx * 8;
        float4 o0, o1;
        o0.x = sq0.x - 2.f * acc0[ri].x; o0.y = sq0.y - 2.f * acc0[ri].y;
        o0.z = sq0.z - 2.f * acc0[ri].z; o0.w = sq0.w - 2.f * acc0[ri].w;
        o1.x = sq1.x - 2.f * acc1[ri].x; o1.y = sq1.y - 2.f * acc1[ri].y;
        o1.z = sq1.z - 2.f * acc1[ri].z; o1.w = sq1.w - 2.f * acc1[ri].w;
        *(float4*)dp = o0;
        *(float4*)(dp + 4) = o1;
    }
}

// ---------------------------------------------------------------- top-20 select: one wave per row
__global__ __launch_bounds__(256) void k_select(const float* __restrict__ dist,
                                                int* __restrict__ idxout, int pass) {
    const int w = threadIdx.x >> 6, lane = threadIdx.x & 63;
    const int rowlocal = blockIdx.x * 4 + w;          // 0..8191 per pass
    const size_t base = (size_t)rowlocal * NP;
    const int growrow = pass * 8 * NP + rowlocal;

    unsigned long long pk[16];
    const float4* dp = (const float4*)(dist + base + lane * 16);
#pragma unroll
    for (int q = 0; q < 4; q++) {
        float4 v = dp[q];
        int jb = lane * 16 + q * 4;
        pk[q * 4 + 0] = ((unsigned long long)ford(v.x) << 32) | (unsigned)(jb + 0);
        pk[q * 4 + 1] = ((unsigned long long)ford(v.y) << 32) | (unsigned)(jb + 1);
        pk[q * 4 + 2] = ((unsigned long long)ford(v.z) << 32) | (unsigned)(jb + 2);
        pk[q * 4 + 3] = ((unsigned long long)ford(v.w) << 32) | (unsigned)(jb + 3);
    }
    unsigned msk = 0;
#pragma unroll 1
    for (int it = 0; it < 20; it++) {
        unsigned long long m = 0xFFFFFFFFFFFFFFFFULL;
#pragma unroll
        for (int t = 0; t < 16; t++) {
            unsigned long long v = (msk & (1u << t)) ? 0xFFFFFFFFFFFFFFFFULL : pk[t];
            m = (v < m) ? v : m;
        }
#pragma unroll
        for (int o = 32; o; o >>= 1) {
            unsigned long long v = __shfl_xor(m, o);
            m = (v < m) ? v : m;
        }
        unsigned wj = (unsigned)(m & 0xFFFFFFFFu);
        if (lane == (int)(wj >> 4)) msk |= 1u << (wj & 15u);
        if (lane == 0) idxout[(size_t)growrow * 20 + it] = (int)wj;
    }
}

// ---------------------------------------------------------------- p/q GEMM (64-tile 4x4; small, unchanged)
template<int D, int DOUT>
__global__ __launch_bounds__(256) void k_gemm_pq(const float* __restrict__ x, int stride,
                                                 const float* __restrict__ wc, const float* __restrict__ b2,
                                                 float* __restrict__ pq) {
    constexpr int N2 = 2 * DOUT;
    constexpr int KC = (D > 64) ? 64 : D;
    __shared__ __align__(16) float At[KC * 68];
    __shared__ __align__(16) float Bs[KC * 64];
    const int tid = threadIdx.x;
    const int tx = tid & 15, ty = tid >> 4;
    const int r0 = blockIdx.x * 64;
    const int c0 = blockIdx.y * 64;

    float4 acc[4] = {};
    for (int k0 = 0; k0 < D; k0 += KC) {
        __syncthreads();
        if constexpr (KC % 4 == 0) {
            constexpr int K4 = KC / 4;
            for (int e = tid; e < 64 * K4; e += 256) {
                int rr = e / K4, kq = e % K4;
                float4 v = *(const float4*)(x + (size_t)(r0 + rr) * stride + k0 + kq * 4);
                At[(4 * kq + 0) * 68 + rr] = v.x;
                At[(4 * kq + 1) * 68 + rr] = v.y;
                At[(4 * kq + 2) * 68 + rr] = v.z;
                At[(4 * kq + 3) * 68 + rr] = v.w;
            }
        } else {
            for (int e = tid; e < 64 * KC; e += 256) {
                int rr = e / KC, kk = e % KC;
                At[kk * 68 + rr] = x[(size_t)(r0 + rr) * stride + k0 + kk];
            }
        }
        for (int e = tid; e < KC * 16; e += 256) {
            int kk = e / 16, cq = e % 16;
            *(float4*)&Bs[kk * 64 + cq * 4] = *(const float4*)(wc + (size_t)(k0 + kk) * N2 + c0 + cq * 4);
        }
        __syncthreads();
#pragma unroll 8
        for (int kk = 0; kk < KC; kk++) {
            float4 a = *(const float4*)&At[kk * 68 + ty * 4];
            float4 bv = *(const float4*)&Bs[kk * 64 + tx * 4];
            FMA16(a, bv);
        }
    }
    float4 bias = *(const float4*)(b2 + c0 + tx * 4);
#pragma unroll
    for (int ri = 0; ri < 4; ri++) {
        float4 o;
        o.x = acc[ri].x + bias.x; o.y = acc[ri].y + bias.y;
        o.z = acc[ri].z + bias.z; o.w = acc[ri].w + bias.w;
        *(float4*)(pq + (size_t)(r0 + ty * 4 + ri) * N2 + c0 + tx * 4) = o;
    }
}

// ---------------------------------------------------------------- gather + max over 20 neighbors
__global__ void k_gather(const float* __restrict__ pq, const int* __restrict__ idx,
                         float* __restrict__ cat_, int log2dout, int off) {
    int gid = blockIdx.x * 256 + threadIdx.x;
    int dout = 1 << log2dout;
    int row = gid >> log2dout;
    int c = gid & (dout - 1);
    int b = row >> 10;
    int s2 = dout * 2;
    const float* qb = pq + (size_t)(b << 10) * s2 + dout + c;
    const int* ip = idx + (size_t)row * 20;
    float m = -FLT_MAX;
#pragma unroll
    for (int t = 0; t < 20; t++) {
        int j = ip[t];
        m = fmaxf(m, qb[(size_t)j * s2]);
    }
    cat_[(size_t)row * 512 + off + c] = pq[(size_t)row * s2 + c] + m;
}

// ---------------------------------------------------------------- fused linear, 128x128 tile, 8x8/thread
// grid (8 col-tiles, 128 row-blocks); stats: colsum/colsq atomics + per (slice,cloud,col) max/min
__global__ __launch_bounds__(256) void k_fused_lin(const float* __restrict__ cat_, const float* __restrict__ Wl,
                                                   const float* __restrict__ bl,
                                                   float* colsum, float* colsq, float* pmax, float* pmin) {
    __shared__ __align__(16) float At[32 * 132];
    __shared__ __align__(16) float Bs[32 * 132];
    __shared__ float red[16 * 128];
    const int tid = threadIdx.x;
    const int tx = tid & 15, ty = tid >> 4;
    const int c0 = blockIdx.x * 128;
    const int rb = blockIdx.y;
    const int r0 = rb * 128;

    float4 acc0[8] = {}, acc1[8] = {};
    for (int kt = 0; kt < 16; kt++) {
        __syncthreads();
        for (int e = tid; e < 128 * 8; e += 256) {
            int rr = e >> 3, kq = e & 7;
            float4 v = *(const float4*)(cat_ + (size_t)(r0 + rr) * 512 + kt * 32 + kq * 4);
            At[(4 * kq + 0) * 132 + rr] = v.x;
            At[(4 * kq + 1) * 132 + rr] = v.y;
            At[(4 * kq + 2) * 132 + rr] = v.z;
            At[(4 * kq + 3) * 132 + rr] = v.w;
        }
        for (int e = tid; e < 32 * 32; e += 256) {
            int kk = e >> 5, cq = e & 31;
            *(float4*)&Bs[kk * 132 + cq * 4] = *(const float4*)(Wl + (size_t)(kt * 32 + kk) * 1024 + c0 + cq * 4);
        }
        __syncthreads();
#pragma unroll 4
        for (int kk = 0; kk < 32; kk++) {
            float4 a0 = *(const float4*)&At[kk * 132 + ty * 8];
            float4 a1 = *(const float4*)&At[kk * 132 + ty * 8 + 4];
            float4 b0 = *(const float4*)&Bs[kk * 132 + tx * 8];
            float4 b1 = *(const float4*)&Bs[kk * 132 + tx * 8 + 4];
            FMA8(acc0[0], acc1[0], a0.x, b0, b1);
            FMA8(acc0[1], acc1[1], a0.y, b0, b1);
            FMA8(acc0[2], acc1[2], a0.z, b0, b1);
            FMA8(acc0[3], acc1[3], a0.w, b0, b1);
            FMA8(acc0[4], acc1[4], a1.x, b0, b1);
            FMA8(acc0[5], acc1[5], a1.y, b0, b1);
            FMA8(acc0[6], acc1[6], a1.z, b0, b1);
            FMA8(acc0[7], acc1[7], a1.w, b0, b1);
        }
    }

    float4 bl0 = *(const float4*)(bl + c0 + tx * 8);
    float4 bl1 = *(const float4*)(bl + c0 + tx * 8 + 4);
    float4 s0 = {0,0,0,0}, s1 = {0,0,0,0}, ss0 = {0,0,0,0}, ss1 = {0,0,0,0};
    float4 mx0 = {-FLT_MAX,-FLT_MAX,-FLT_MAX,-FLT_MAX}, mx1 = mx0;
    float4 mn0 = {FLT_MAX,FLT_MAX,FLT_MAX,FLT_MAX}, mn1 = mn0;
#pragma unroll
    for (int ri = 0; ri < 8; ri++) {
        float4 y0, y1;
        y0.x = acc0[ri].x + bl0.x; y0.y = acc0[ri].y + bl0.y;
        y0.z = acc0[ri].z + bl0.z; y0.w = acc0[ri].w + bl0.w;
        y1.x = acc1[ri].x + bl1.x; y1.y = acc1[ri].y + bl1.y;
        y1.z = acc1[ri].z + bl1.z; y1.w = acc1[ri].w + bl1.w;
        s0.x += y0.x; ss0.x += y0.x*y0.x; mx0.x = fmaxf(mx0.x, y0.x); mn0.x = fminf(mn0.x, y0.x);
        s0.y += y0.y; ss0.y += y0.y*y0.y; mx0.y = fmaxf(mx0.y, y0.y); mn0.y = fminf(mn0.y, y0.y);
        s0.z += y0.z; ss0.z += y0.z*y0.z; mx0.z = fmaxf(mx0.z, y0.z); mn0.z = fminf(mn0.z, y0.z);
        s0.w += y0.w; ss0.w += y0.w*y0.w; mx0.w = fmaxf(mx0.w, y0.w); mn0.w = fminf(mn0.w, y0.w);
        s1.x += y1.x; ss1.x += y1.x*y1.x; mx1.x = fmaxf(mx1.x, y1.x); mn1.x = fminf(mn1.x, y1.x);
        s1.y += y1.y; ss1.y += y1.y*y1.y; mx1.y = fmaxf(mx1.y, y1.y); mn1.y = fminf(mn1.y, y1.y);
        s1.z += y1.z; ss1.z += y1.z*y1.z; mx1.z = fmaxf(mx1.z, y1.z); mn1.z = fminf(mn1.z, y1.z);
        s1.w += y1.w; ss1.w += y1.w*y1.w; mx1.w = fmaxf(mx1.w, y1.w); mn1.w = fminf(mn1.w, y1.w);
    }

    float rsum = 0.f, rss = 0.f, rmx = -FLT_MAX, rmn = FLT_MAX;
    __syncthreads();
    *(float4*)&red[ty * 128 + tx * 8] = s0; *(float4*)&red[ty * 128 + tx * 8 + 4] = s1;
    __syncthreads();
    if (tid < 128) for (int t = 0; t < 16; t++) rsum += red[t * 128 + tid];
    __syncthreads();
    *(float4*)&red[ty * 128 + tx * 8] = ss0; *(float4*)&red[ty * 128 + tx * 8 + 4] = ss1;
    __syncthreads();
    if (tid < 128) for (int t = 0; t < 16; t++) rss += red[t * 128 + tid];
    __syncthreads();
    *(float4*)&red[ty * 128 + tx * 8] = mx0; *(float4*)&red[ty * 128 + tx * 8 + 4] = mx1;
    __syncthreads();
    if (tid < 128) for (int t = 0; t < 16; t++) rmx = fmaxf(rmx, red[t * 128 + tid]);
    __syncthreads();
    *(float4*)&red[ty * 128 + tx * 8] = mn0; *(float4*)&red[ty * 128 + tx * 8 + 4] = mn1;
    __syncthreads();
    if (tid < 128) for (int t = 0; t < 16; t++) rmn = fminf(rmn, red[t * 128 + tid]);

    if (tid < 128) {
        int c = c0 + tid;
        int b = rb >> 3, slice = rb & 7;
        atomicAdd(&colsum[c], rsum);
        atomicAdd(&colsq[c], rss);
        pmax[(size_t)(slice * 16 + b) * 1024 + c] = rmx;
        pmin[(size_t)(slice * 16 + b) * 1024 + c] = rmn;
    }
}

// ---------------------------------------------------------------- BN + leaky + pool (commuted through max/min; 8 slices)
__global__ void k_bnpool(const float* colsum, const float* colsq,
                         const float* pmax, const float* pmin,
                         const float* __restrict__ gl, const float* __restrict__ betal,
                         float* __restrict__ pooled) {
    int gid = blockIdx.x * 256 + threadIdx.x;   // 16384
    int c = gid & 1023, b = gid >> 10;
    float mean = colsum[c] * (1.f / 16384.f);
    float var = colsq[c] * (1.f / 16384.f) - mean * mean;
    float a = gl[c] * rsqrtf(var + 1e-5f);
    float d = betal[c] - mean * a;
    float vmx = -FLT_MAX, vmn = FLT_MAX;
#pragma unroll
    for (int rs = 0; rs < 8; rs++) {
        vmx = fmaxf(vmx, pmax[(size_t)(rs * 16 + b) * 1024 + c]);
        vmn = fminf(vmn, pmin[(size_t)(rs * 16 + b) * 1024 + c]);
    }
    float v = a * ((a >= 0.f) ? vmx : vmn) + d;
    pooled[gid] = v > 0.f ? v : 0.2f * v;
}

// ---------------------------------------------------------------- MLP stage 1
__global__ __launch_bounds__(256) void k_mlp1(const float* __restrict__ pooled, const float* __restrict__ Wm1,
                                              const float* __restrict__ bm1, const float* __restrict__ gm1,
                                              const float* __restrict__ betam1, float* __restrict__ hbuf) {
    int tid = threadIdx.x;
    int r = tid >> 4, cl = tid & 15;
    int c = blockIdx.x * 16 + cl;
    float z = bm1[c];
    const float* pr = pooled + (size_t)r * 1024;
    for (int kk = 0; kk < 1024; kk++) z += pr[kk] * Wm1[(size_t)kk * 512 + c];
    __shared__ float zb[16 * 16];
    zb[r * 16 + cl] = z;
    __syncthreads();
    float sm = 0.f, sq = 0.f;
#pragma unroll
    for (int rr = 0; rr < 16; rr++) { float v = zb[rr * 16 + cl]; sm += v; sq += v * v; }
    float mean = sm * (1.f / 16.f);
    float var = sq * (1.f / 16.f) - mean * mean;
    float h = gm1[c] * (z - mean) * rsqrtf(var + 1e-5f) + betam1[c];
    hbuf[(size_t)r * 512 + c] = h > 0.f ? h : 0.2f * h;
}

// ---------------------------------------------------------------- MLP stage 2
__global__ void k_mlp2(const float* __restrict__ hbuf, const float* __restrict__ Wm2,
                       const float* __restrict__ bm2, float* __restrict__ out) {
    int gid = blockIdx.x * 256 + threadIdx.x;
    if (gid >= 640) return;
    int r = gid / 40, c = gid % 40;
    float o = bm2[c];
    const float* hr = hbuf + (size_t)r * 512;
    for (int kk = 0; kk < 512; kk++) o += hr[kk] * Wm2[(size_t)kk * 40 + c];
    out[gid] = o;
}

// ----------------------------------------------------------------
extern "C" void kernel_launch(void* const* d_in, const int* in_sizes, int n_in,
                              void* d_out, int out_size, void* d_ws, size_t ws_size,
                              hipStream_t stream) {
    const float* pos = (const float*)d_in[0];
    const float* W1 = (const float*)d_in[2];
    const float* b1 = (const float*)d_in[3];
    const float* W2 = (const float*)d_in[4];
    const float* b2 = (const float*)d_in[5];
    const float* W3 = (const float*)d_in[6];
    const float* b3 = (const float*)d_in[7];
    const float* W4 = (const float*)d_in[8];
    const float* b4 = (const float*)d_in[9];
    const float* Wl = (const float*)d_in[10];
    const float* bl = (const float*)d_in[11];
    const float* gl = (const float*)d_in[12];
    const float* betal = (const float*)d_in[13];
    const float* Wm1 = (const float*)d_in[14];
    const float* bm1 = (const float*)d_in[15];
    const float* gm1 = (const float*)d_in[16];
    const float* betam1 = (const float*)d_in[17];
    const float* Wm2 = (const float*)d_in[18];
    const float* bm2 = (const float*)d_in[19];
    float* out = (float*)d_out;

    float* ws = (float*)d_ws;
    float* cat_ = ws;                                   // 16384*512
    float* pq = cat_ + (size_t)NROW * 512;              // 16384*512 (aliased by dist, then pmax/pmin)
    int* idx = (int*)(pq + (size_t)NROW * 512);         // 16384*20
    float* sqb = (float*)(idx + NROW * 20);             // 16384
    float* wc1 = sqb + NROW;
    float* wc2 = wc1 + 3 * 128;
    float* wc3 = wc2 + 64 * 128;
    float* wc4 = wc3 + 64 * 256;
    float* bb1 = wc4 + 128 * 512;
    float* bb2 = bb1 + 128;
    float* bb3 = bb2 + 128;
    float* bb4 = bb3 + 256;
    float* colsum = bb4 + 512;
    float* colsq = colsum + 1024;
    float* pooled = colsq + 1024;                       // 16384
    float* hbuf = pooled + NROW;                        // 8192
    size_t need = (size_t)((hbuf + 16 * 512) - ws) * sizeof(float);
    if (ws_size < need) return;

    float* dist = pq;                 // 8*1024*1024 floats; dead after select
    float* pmax = pq;                 // 8*16*1024, alias pq after final gather
    float* pmin = pq + 8 * 16 * 1024;

    k_prep<<<256, 256, 0, stream>>>(W1, b1, wc1, bb1, 3, 64);
    k_prep<<<256, 256, 0, stream>>>(W2, b2, wc2, bb2, 64, 64);
    k_prep<<<256, 256, 0, stream>>>(W3, b3, wc3, bb3, 64, 128);
    k_prep<<<256, 256, 0, stream>>>(W4, b4, wc4, bb4, 128, 256);

    // layer 1 (D=3 -> 64)
    k_sqnorm<<<4096, 256, 0, stream>>>(pos, 3, 3, sqb);
    for (int p = 0; p < 2; p++) {
        k_dist<3><<<dim3(8, 8, 8), 256, 0, stream>>>(pos, 3, sqb, dist, p);
        k_select<<<2048, 256, 0, stream>>>(dist, idx, p);
    }
    k_gemm_pq<3, 64><<<dim3(256, 2), 256, 0, stream>>>(pos, 3, wc1, bb1, pq);
    k_gather<<<4096, 256, 0, stream>>>(pq, idx, cat_, 6, 0);
    // layer 2 (64 -> 64)
    k_sqnorm<<<4096, 256, 0, stream>>>(cat_, 512, 64, sqb);
    for (int p = 0; p < 2; p++) {
        k_dist<64><<<dim3(8, 8, 8), 256, 0, stream>>>(cat_, 512, sqb, dist, p);
        k_select<<<2048, 256, 0, stream>>>(dist, idx, p);
    }
    k_gemm_pq<64, 64><<<dim3(256, 2), 256, 0, stream>>>(cat_, 512, wc2, bb2, pq);
    k_gather<<<4096, 256, 0, stream>>>(pq, idx, cat_, 6, 64);
    // layer 3 (64 -> 128)
    k_sqnorm<<<4096, 256, 0, stream>>>(cat_ + 64, 512, 64, sqb);
    for (int p = 0; p < 2; p++) {
        k_dist<64><<<dim3(8, 8, 8), 256, 0, stream>>>(cat_ + 64, 512, sqb, dist, p);
        k_select<<<2048, 256, 0, stream>>>(dist, idx, p);
    }
    k_gemm_pq<64, 128><<<dim3(256, 4), 256, 0, stream>>>(cat_ + 64, 512, wc3, bb3, pq);
    k_gather<<<8192, 256, 0, stream>>>(pq, idx, cat_, 7, 128);
    // layer 4 (128 -> 256)
    k_sqnorm<<<4096, 256, 0, stream>>>(cat_ + 128, 512, 128, sqb);
    for (int p = 0; p < 2; p++) {
        k_dist<128><<<dim3(8, 8, 8), 256, 0, stream>>>(cat_ + 128, 512, sqb, dist, p);
        k_select<<<2048, 256, 0, stream>>>(dist, idx, p);
    }
    k_gemm_pq<128, 256><<<dim3(256, 8), 256, 0, stream>>>(cat_ + 128, 512, wc4, bb4, pq);
    k_gather<<<16384, 256, 0, stream>>>(pq, idx, cat_, 8, 256);

    // pq now dead; pmax/pmin alias it
    k_init<<<512, 256, 0, stream>>>(colsum, colsq, pmax, pmin);
    k_fused_lin<<<dim3(8, 128), 256, 0, stream>>>(cat_, Wl, bl, colsum, colsq, pmax, pmin);
    k_bnpool<<<64, 256, 0, stream>>>(colsum, colsq, pmax, pmin, gl, betal, pooled);
    k_mlp1<<<32, 256, 0, stream>>>(pooled, Wm1, bm1, gm1, betam1, hbuf);
    k_mlp2<<<3, 256, 0, stream>>>(hbuf, Wm2, bm2, out);
}